// Round 2
// baseline (172.264 us; speedup 1.0000x reference)
//
#include <hip/hip_runtime.h>

#define BATCH 16
#define HH 512
#define WW 512
#define RSLICE 8
#define NSLICE (HH / RSLICE)   // 64

static constexpr size_t PLANE = (size_t)HH * WW;
static constexpr size_t COLP_ELEMS = (size_t)BATCH * NSLICE * WW; // 524288 floats (2 MB)
static constexpr size_t ROWS_ELEMS = (size_t)BATCH * HH;          // 8192 floats

// Per-row register buffer: ref/tgt x 3 channels, 4 columns each (float4),
// plus the boundary column (col 4t+4) scalars for the wave-edge lane (t==63).
struct RowBuf {
  float4 r0, r1, r2, t0, t1, t2;
  float br0, br1, br2, bt0, bt1, bt2;
};

__device__ __forceinline__ void load_row(RowBuf& B, const float* __restrict__ rb,
                                         const float* __restrict__ tb, int row,
                                         int t, bool bnd) {
  const size_t o = (size_t)row * WW + 4 * t;
  B.r0 = *(const float4*)(rb + o);
  B.r1 = *(const float4*)(rb + o + PLANE);
  B.r2 = *(const float4*)(rb + o + 2 * PLANE);
  B.t0 = *(const float4*)(tb + o);
  B.t1 = *(const float4*)(tb + o + PLANE);
  B.t2 = *(const float4*)(tb + o + 2 * PLANE);
  if (bnd) {
    const size_t ob = o + 4;
    B.br0 = rb[ob]; B.br1 = rb[ob + PLANE]; B.br2 = rb[ob + 2 * PLANE];
    B.bt0 = tb[ob]; B.bt1 = tb[ob + PLANE]; B.bt2 = tb[ob + 2 * PLANE];
  }
}

__device__ __forceinline__ float lum3(float a, float b, float c) {
  return 0.299f * a + 0.587f * b + 0.114f * c;
}

// Kernel A: block = (batch, 8-row slice); 128 threads, thread owns cols
// 4t..4t+3 (float4, 16B/lane). 1024 blocks -> 8 blocks/CU -> 16 waves/CU.
// Fully-unrolled 9-row loop with alternating named buffers: prefetch for row
// i+2 issues into the just-consumed buffer, so only counted vmcnt waits are
// needed (no full drain per row).
__global__ __launch_bounds__(128, 4) void jbd_reduce(const float* __restrict__ ref,
                                                     const float* __restrict__ tgt,
                                                     float* __restrict__ colp,
                                                     float* __restrict__ rows) {
  const int t = threadIdx.x;          // 0..127
  const int lane = t & 63;
  const int wid = t >> 6;
  const bool bnd = (t == 63);         // lane 63 of wave 0 needs col 256
  const int slice = blockIdx.x & (NSLICE - 1);
  const int b = blockIdx.x >> 6;      // / NSLICE
  const int r0 = slice * RSLICE;
  const float* rb = ref + (size_t)b * 3 * PLANE;
  const float* tb = tgt + (size_t)b * 3 * PLANE;
  __shared__ float rowpart[RSLICE][2];

  float ca0 = 0.f, ca1 = 0.f, ca2 = 0.f, ca3 = 0.f;   // per-column de_h sums
  float plr0 = 0.f, plr1 = 0.f, plr2 = 0.f, plr3 = 0.f; // prev-row lum (ref)
  float plt0 = 0.f, plt1 = 0.f, plt2 = 0.f, plt3 = 0.f; // prev-row lum (tgt)

  RowBuf X, Y;
  load_row(X, rb, tb, r0, t, bnd);
  load_row(Y, rb, tb, r0 + 1, t, bnd);   // r0+1 <= 505, always valid

#pragma unroll
  for (int i = 0; i <= RSLICE; ++i) {
    RowBuf& C = (i & 1) ? Y : X;         // i is unroll-constant -> static
    const float a0 = lum3(C.r0.x, C.r1.x, C.r2.x);
    const float a1 = lum3(C.r0.y, C.r1.y, C.r2.y);
    const float a2 = lum3(C.r0.z, C.r1.z, C.r2.z);
    const float a3 = lum3(C.r0.w, C.r1.w, C.r2.w);
    const float c0 = lum3(C.t0.x, C.t1.x, C.t2.x);
    const float c1 = lum3(C.t0.y, C.t1.y, C.t2.y);
    const float c2 = lum3(C.t0.z, C.t1.z, C.t2.z);
    const float c3 = lum3(C.t0.w, C.t1.w, C.t2.w);
    float blr = 0.f, blt = 0.f;
    if (bnd) {
      blr = lum3(C.br0, C.br1, C.br2);
      blt = lum3(C.bt0, C.bt1, C.bt2);
    }
    // prefetch row r0+i+2 into the buffer just consumed (regs now free)
    if (i + 2 <= RSLICE)
      load_row(C, rb, tb, min(r0 + i + 2, HH - 1), t, bnd);
    // horizontal neighbor (col 4t+4) luminance via next lane's col 0
    float nlr = __shfl_down(a0, 1);
    float nlt = __shfl_down(c0, 1);
    if (bnd) { nlr = blr; nlt = blt; }
    if (i < RSLICE) {                    // de_h for this block's own rows
      ca0 += fmaxf(fabsf(c0 - c1) - fabsf(a0 - a1), 0.f);
      ca1 += fmaxf(fabsf(c1 - c2) - fabsf(a1 - a2), 0.f);
      ca2 += fmaxf(fabsf(c2 - c3) - fabsf(a2 - a3), 0.f);
      if (t < 127)                       // col 511 has no de_h
        ca3 += fmaxf(fabsf(c3 - nlt) - fabsf(a3 - nlr), 0.f);
    }
    if (i >= 1 && (r0 + i) < HH) {       // de_v for row r0+i-1
      float dv = fmaxf(fabsf(c0 - plt0) - fabsf(a0 - plr0), 0.f)
               + fmaxf(fabsf(c1 - plt1) - fabsf(a1 - plr1), 0.f)
               + fmaxf(fabsf(c2 - plt2) - fabsf(a2 - plr2), 0.f)
               + fmaxf(fabsf(c3 - plt3) - fabsf(a3 - plr3), 0.f);
      dv += __shfl_xor(dv, 1);
      dv += __shfl_xor(dv, 2);
      dv += __shfl_xor(dv, 4);
      dv += __shfl_xor(dv, 8);
      dv += __shfl_xor(dv, 16);
      dv += __shfl_xor(dv, 32);
      if (lane == 0) rowpart[i - 1][wid] = dv;
    }
    plr0 = a0; plr1 = a1; plr2 = a2; plr3 = a3;
    plt0 = c0; plt1 = c1; plt2 = c2; plt3 = c3;
  }
  __syncthreads();
  if (t < RSLICE) {
    const int h = r0 + t;
    if (h < HH - 1)                      // de_v rows are 0..510
      rows[(size_t)b * HH + h] = rowpart[t][0] + rowpart[t][1];
  }
  *(float4*)&colp[((size_t)b * NSLICE + slice) * WW + 4 * t] =
      make_float4(ca0, ca1, ca2, ca3);
}

// Kernel B: block per (direction, batch), 64 threads. Thread t owns the 8
// consecutive lines 8t..8t+7, so line j has phase j directly. float4 loads,
// per-phase butterfly reduce over 64 lanes, then uniform 8-way argmax.
__global__ __launch_bounds__(64) void jbd_phase(const float* __restrict__ colp,
                                                const float* __restrict__ rows,
                                                int* __restrict__ results) {
  const int dir = blockIdx.x & 1;   // 0 = columns (de_h), 1 = rows (de_v)
  const int b = blockIdx.x >> 1;
  const int t = threadIdx.x;        // 0..63
  float c0 = 0.f, c1 = 0.f, c2 = 0.f, c3 = 0.f;
  float c4 = 0.f, c5 = 0.f, c6 = 0.f, c7 = 0.f;
  if (dir == 0) {
#pragma unroll 4
    for (int sl = 0; sl < NSLICE; ++sl) {
      const float* p = colp + ((size_t)b * NSLICE + sl) * WW + 8 * t;
      const float4 u = *(const float4*)p;
      const float4 v = *(const float4*)(p + 4);
      c0 += u.x; c1 += u.y; c2 += u.z; c3 += u.w;
      c4 += v.x; c5 += v.y; c6 += v.z; c7 += v.w;
    }
  } else {
    const float* p = rows + (size_t)b * HH + 8 * t;
    const float4 u = *(const float4*)p;
    const float4 v = *(const float4*)(p + 4);
    c0 = u.x; c1 = u.y; c2 = u.z; c3 = u.w;
    c4 = v.x; c5 = v.y; c6 = v.z; c7 = v.w;
  }
  if (t == 63) c7 = 0.f;            // line 511 does not exist (511 lines: 0..510)
  float ps[8] = {c0, c1, c2, c3, c4, c5, c6, c7};
  float tot = 0.f;
#pragma unroll
  for (int p = 0; p < 8; ++p) {
    float v = ps[p];
    v += __shfl_xor(v, 1);
    v += __shfl_xor(v, 2);
    v += __shfl_xor(v, 4);
    v += __shfl_xor(v, 8);
    v += __shfl_xor(v, 16);
    v += __shfl_xor(v, 32);
    v *= (1.0f / 512.0f);           // line mean divisor (H resp. W = 512)
    ps[p] = v;                      // sums[p] in reference terms
    tot += v;
  }
  float best = -1.f;
  int bk = 0;
#pragma unroll
  for (int p = 0; p < 8; ++p) {
    const float cnt = (p == 7) ? 63.f : 64.f;  // 511 lines: phase 7 has 63
    const float a_k = ps[p] / cnt;
    const float bg = (tot - ps[p]) / (511.f - cnt);
    const float r = a_k / (bg + 1e-8f);
    if (r > best) { best = r; bk = p; }        // strict > = first-index tie-break
  }
  if (t == 0) {
    results[4 * b + 2 * dir] = bk;
    results[4 * b + 2 * dir + 1] = (best > (float)(1.0 / 0.35)) ? 1 : 0;
  }
}

// Kernel C: broadcast per-batch decisions to the (B,1,H,W) mask, float4 stores.
__global__ __launch_bounds__(256) void jbd_write(const int* __restrict__ results,
                                                 float* __restrict__ out) {
  const int idx = blockIdx.x * 256 + threadIdx.x;  // float4 index
  const int b = idx >> 16;          // 512*128 float4 per batch
  const int rem = idx & 65535;
  const int h = rem >> 7;
  const int wq = rem & 127;
  const int4 rs = ((const int4*)results)[b];  // {bk_h, blocked_h, bk_v, blocked_v}
  const bool rowm = (rs.w != 0) && ((h & 7) == rs.z) && (h < HH - 1);
  float4 o;
  float* po = (float*)&o;
  const int w0 = wq << 2;
#pragma unroll
  for (int j = 0; j < 4; ++j) {
    const int w = w0 + j;
    const bool colm = (rs.y != 0) && ((w & 7) == rs.x) && (w < WW - 1);
    po[j] = (rowm || colm) ? 1.0f : 0.0f;
  }
  ((float4*)out)[idx] = o;
}

extern "C" void kernel_launch(void* const* d_in, const int* in_sizes, int n_in,
                              void* d_out, int out_size, void* d_ws, size_t ws_size,
                              hipStream_t stream) {
  (void)in_sizes; (void)n_in; (void)out_size; (void)ws_size;
  const float* ref = (const float*)d_in[0];
  const float* tgt = (const float*)d_in[1];
  float* colp = (float*)d_ws;                 // [B][NSLICE][W]
  float* rows = colp + COLP_ELEMS;            // [B][H] (index 511 unused)
  int* results = (int*)(rows + ROWS_ELEMS);   // [B][4]
  jbd_reduce<<<BATCH * NSLICE, 128, 0, stream>>>(ref, tgt, colp, rows);
  jbd_phase<<<2 * BATCH, 64, 0, stream>>>(colp, rows, results);
  jbd_write<<<(BATCH * HH * WW / 4) / 256, 256, 0, stream>>>(results, (float*)d_out);
}

// Round 3
// 135.971 us; speedup vs baseline: 1.2669x; 1.2669x over previous
//
#include <hip/hip_runtime.h>

#define BATCH 16
#define HH 512
#define WW 512
#define RSLICE 8
#define NSLICE (HH / RSLICE)   // 64

static constexpr size_t PLANE = (size_t)HH * WW;
static constexpr size_t COLP_ELEMS = (size_t)BATCH * NSLICE * WW; // 524288 floats (2 MB)
static constexpr size_t ROWS_ELEMS = (size_t)BATCH * HH;          // 8192 floats

// Per-row register buffer: ref/tgt x 3 channels, 2 columns each (float2, 8B
// loads), plus the boundary column (col 2t+2) scalars for wave-edge lanes.
// 18 floats per buffer -> two buffers + lums + accumulators ~70 VGPRs: no
// spill at the default allocator budget (no min-occupancy launch_bounds
// hint -- round 2's (128,4) hint clamped VGPRs to 64 and spilled 240 B/thread,
// visible as 31.6 MB of scratch WRITE_SIZE).
struct RowBuf {
  float2 r0, r1, r2, t0, t1, t2;
  float br0, br1, br2, bt0, bt1, bt2;
};

__device__ __forceinline__ void load_row(RowBuf& B, const float* __restrict__ rb,
                                         const float* __restrict__ tb, int row,
                                         int t, bool bnd) {
  const size_t o = (size_t)row * WW + 2 * t;
  B.r0 = *(const float2*)(rb + o);
  B.r1 = *(const float2*)(rb + o + PLANE);
  B.r2 = *(const float2*)(rb + o + 2 * PLANE);
  B.t0 = *(const float2*)(tb + o);
  B.t1 = *(const float2*)(tb + o + PLANE);
  B.t2 = *(const float2*)(tb + o + 2 * PLANE);
  if (bnd) {
    const size_t ob = o + 2;
    B.br0 = rb[ob]; B.br1 = rb[ob + PLANE]; B.br2 = rb[ob + 2 * PLANE];
    B.bt0 = tb[ob]; B.bt1 = tb[ob + PLANE]; B.bt2 = tb[ob + 2 * PLANE];
  }
}

__device__ __forceinline__ float lum3(float a, float b, float c) {
  return 0.299f * a + 0.587f * b + 0.114f * c;
}

// Kernel A: block = (batch, 8-row slice); 256 threads, thread owns cols
// 2t, 2t+1. Grid = 16*64 = 1024 blocks x 4 waves = 16 waves/CU (TLP hides
// HBM latency). Fully-unrolled 9-row loop, alternating named buffers X/Y:
// prefetch for row i+2 issues into the just-consumed buffer.
__global__ __launch_bounds__(256) void jbd_reduce(const float* __restrict__ ref,
                                                  const float* __restrict__ tgt,
                                                  float* __restrict__ colp,
                                                  float* __restrict__ rows) {
  const int t = threadIdx.x;          // 0..255
  const int lane = t & 63;
  const int wid = t >> 6;
  const bool bnd = (lane == 63) && (t != 255);  // needs next wave's col 2t+2
  const int slice = blockIdx.x & (NSLICE - 1);
  const int b = blockIdx.x >> 6;      // / NSLICE
  const int r0 = slice * RSLICE;
  const float* rb = ref + (size_t)b * 3 * PLANE;
  const float* tb = tgt + (size_t)b * 3 * PLANE;
  __shared__ float rowpart[RSLICE][4];

  float ca0 = 0.f, ca1 = 0.f;                     // per-column de_h sums
  float plr0 = 0.f, plr1 = 0.f, plt0 = 0.f, plt1 = 0.f;  // prev-row lums

  RowBuf X, Y;
  load_row(X, rb, tb, r0, t, bnd);
  load_row(Y, rb, tb, r0 + 1, t, bnd);   // r0+1 <= 505, always valid

#pragma unroll
  for (int i = 0; i <= RSLICE; ++i) {
    RowBuf& C = (i & 1) ? Y : X;         // i is unroll-constant -> static
    const float a0 = lum3(C.r0.x, C.r1.x, C.r2.x);
    const float a1 = lum3(C.r0.y, C.r1.y, C.r2.y);
    const float c0 = lum3(C.t0.x, C.t1.x, C.t2.x);
    const float c1 = lum3(C.t0.y, C.t1.y, C.t2.y);
    float blr = 0.f, blt = 0.f;
    if (bnd) {
      blr = lum3(C.br0, C.br1, C.br2);
      blt = lum3(C.bt0, C.bt1, C.bt2);
    }
    // prefetch row r0+i+2 into the buffer just consumed (regs now free)
    if (i + 2 <= RSLICE)
      load_row(C, rb, tb, min(r0 + i + 2, HH - 1), t, bnd);
    // horizontal neighbor (col 2t+2) luminance via next lane's col 0
    float nlr = __shfl_down(a0, 1);
    float nlt = __shfl_down(c0, 1);
    if (bnd) { nlr = blr; nlt = blt; }
    if (i < RSLICE) {                    // de_h for this block's own rows
      ca0 += fmaxf(fabsf(c0 - c1) - fabsf(a0 - a1), 0.f);
      if (t < 255)                       // col 511 has no de_h
        ca1 += fmaxf(fabsf(c1 - nlt) - fabsf(a1 - nlr), 0.f);
    }
    if (i >= 1 && (r0 + i) < HH) {       // de_v for row r0+i-1
      float dv = fmaxf(fabsf(c0 - plt0) - fabsf(a0 - plr0), 0.f)
               + fmaxf(fabsf(c1 - plt1) - fabsf(a1 - plr1), 0.f);
      dv += __shfl_xor(dv, 1);
      dv += __shfl_xor(dv, 2);
      dv += __shfl_xor(dv, 4);
      dv += __shfl_xor(dv, 8);
      dv += __shfl_xor(dv, 16);
      dv += __shfl_xor(dv, 32);
      if (lane == 0) rowpart[i - 1][wid] = dv;
    }
    plr0 = a0; plr1 = a1; plt0 = c0; plt1 = c1;
  }
  __syncthreads();
  if (t < RSLICE) {
    const int h = r0 + t;
    if (h < HH - 1)                      // de_v rows are 0..510
      rows[(size_t)b * HH + h] =
          rowpart[t][0] + rowpart[t][1] + rowpart[t][2] + rowpart[t][3];
  }
  *(float2*)&colp[((size_t)b * NSLICE + slice) * WW + 2 * t] =
      make_float2(ca0, ca1);
}

// Kernel B: block per (direction, batch), 64 threads. Thread t owns the 8
// consecutive lines 8t..8t+7 (phase = j directly). float4 loads, per-phase
// butterfly reduce, then uniform 8-way argmax (strict > = first-index ties).
__global__ __launch_bounds__(64) void jbd_phase(const float* __restrict__ colp,
                                                const float* __restrict__ rows,
                                                int* __restrict__ results) {
  const int dir = blockIdx.x & 1;   // 0 = columns (de_h), 1 = rows (de_v)
  const int b = blockIdx.x >> 1;
  const int t = threadIdx.x;        // 0..63
  float c0 = 0.f, c1 = 0.f, c2 = 0.f, c3 = 0.f;
  float c4 = 0.f, c5 = 0.f, c6 = 0.f, c7 = 0.f;
  if (dir == 0) {
#pragma unroll 4
    for (int sl = 0; sl < NSLICE; ++sl) {
      const float* p = colp + ((size_t)b * NSLICE + sl) * WW + 8 * t;
      const float4 u = *(const float4*)p;
      const float4 v = *(const float4*)(p + 4);
      c0 += u.x; c1 += u.y; c2 += u.z; c3 += u.w;
      c4 += v.x; c5 += v.y; c6 += v.z; c7 += v.w;
    }
  } else {
    const float* p = rows + (size_t)b * HH + 8 * t;
    const float4 u = *(const float4*)p;
    const float4 v = *(const float4*)(p + 4);
    c0 = u.x; c1 = u.y; c2 = u.z; c3 = u.w;
    c4 = v.x; c5 = v.y; c6 = v.z; c7 = v.w;
  }
  if (t == 63) c7 = 0.f;            // line 511 does not exist (511 lines)
  float ps[8] = {c0, c1, c2, c3, c4, c5, c6, c7};
  float tot = 0.f;
#pragma unroll
  for (int p = 0; p < 8; ++p) {
    float v = ps[p];
    v += __shfl_xor(v, 1);
    v += __shfl_xor(v, 2);
    v += __shfl_xor(v, 4);
    v += __shfl_xor(v, 8);
    v += __shfl_xor(v, 16);
    v += __shfl_xor(v, 32);
    v *= (1.0f / 512.0f);           // line-mean divisor (H resp. W = 512)
    ps[p] = v;
    tot += v;
  }
  float best = -1.f;
  int bk = 0;
#pragma unroll
  for (int p = 0; p < 8; ++p) {
    const float cnt = (p == 7) ? 63.f : 64.f;  // phases 0..6 -> 64 lines, 7 -> 63
    const float a_k = ps[p] / cnt;
    const float bg = (tot - ps[p]) / (511.f - cnt);
    const float r = a_k / (bg + 1e-8f);
    if (r > best) { best = r; bk = p; }
  }
  if (t == 0) {
    results[4 * b + 2 * dir] = bk;
    results[4 * b + 2 * dir + 1] = (best > (float)(1.0 / 0.35)) ? 1 : 0;
  }
}

// Kernel C: broadcast per-batch decisions to the (B,1,H,W) mask, float4 stores.
__global__ __launch_bounds__(256) void jbd_write(const int* __restrict__ results,
                                                 float* __restrict__ out) {
  const int idx = blockIdx.x * 256 + threadIdx.x;  // float4 index
  const int b = idx >> 16;          // 512*128 float4 per batch
  const int rem = idx & 65535;
  const int h = rem >> 7;
  const int wq = rem & 127;
  const int4 rs = ((const int4*)results)[b];  // {bk_h, blocked_h, bk_v, blocked_v}
  const bool rowm = (rs.w != 0) && ((h & 7) == rs.z) && (h < HH - 1);
  float4 o;
  float* po = (float*)&o;
  const int w0 = wq << 2;
#pragma unroll
  for (int j = 0; j < 4; ++j) {
    const int w = w0 + j;
    const bool colm = (rs.y != 0) && ((w & 7) == rs.x) && (w < WW - 1);
    po[j] = (rowm || colm) ? 1.0f : 0.0f;
  }
  ((float4*)out)[idx] = o;
}

extern "C" void kernel_launch(void* const* d_in, const int* in_sizes, int n_in,
                              void* d_out, int out_size, void* d_ws, size_t ws_size,
                              hipStream_t stream) {
  (void)in_sizes; (void)n_in; (void)out_size; (void)ws_size;
  const float* ref = (const float*)d_in[0];
  const float* tgt = (const float*)d_in[1];
  float* colp = (float*)d_ws;                 // [B][NSLICE][W]
  float* rows = colp + COLP_ELEMS;            // [B][H] (index 511 unused)
  int* results = (int*)(rows + ROWS_ELEMS);   // [B][4]
  jbd_reduce<<<BATCH * NSLICE, 256, 0, stream>>>(ref, tgt, colp, rows);
  jbd_phase<<<2 * BATCH, 64, 0, stream>>>(colp, rows, results);
  jbd_write<<<(BATCH * HH * WW / 4) / 256, 256, 0, stream>>>(results, (float*)d_out);
}